// Round 3
// baseline (555.582 us; speedup 1.0000x reference)
//
#include <hip/hip_runtime.h>
#include <cmath>
#include <complex>
#include <vector>
#include <algorithm>
#include <cstring>

// ---------------------------------------------------------------------------
// AtomCenteredTensorMomentDescriptor — two-stage pipeline.
//
// Factorization: basis[m][k] = Y[m] * radcut[k]  (rank-1)  =>
//   y{1,2}[l][i][f] = Y[off(l)+i] * R{1,2}[l][f],  R[l][f] = sum_k radcut[k] W[l][k][f]
//   out[e,k3,f]     = sum_paths R1[l1][f] R2[l2][f] * P[e][slot]
//   P[e][slot]      = sum_nnz CG * Y_i * Y_j              (f-independent!)
//
// Stage 1 (edge_kernel): per-(edge,slot) threads -> P[e][136], radcut[e][8] in d_ws.
//   Massive TLP (~160 waves/SIMD queued) hides the CSR gather latency that made
//   the fused version latency-bound (~262us).
// Stage 2 (feat_kernel): wave per edge, pure streaming write of 419 MB.
//   Floor ~67us @ 6.3 TB/s (harness fill kernels measured at 6.26 TB/s).
// ---------------------------------------------------------------------------

#define MAXNNZ 4096

struct CGTab {
  int   rowPtr[136];   // CSR over 135 P-slots
  int   ij[MAXNNZ];    // packed iGlob | (jGlob<<8), indices into Y[16]
  float co[MAXNNZ];    // CG coefficient
};

__device__ CGTab d_tab;

// ---------------- host-side CG construction (exact port of reference) -------

static double factd(int n) { double f = 1.0; for (int i = 2; i <= n; ++i) f *= (double)i; return f; }

static void cg_complex(int j1, int j2, int j3, std::vector<double>& C) {
  int d2 = 2 * j2 + 1, d3 = 2 * j3 + 1;
  C.assign((2 * j1 + 1) * d2 * d3, 0.0);
  for (int m1 = -j1; m1 <= j1; ++m1)
    for (int m2 = -j2; m2 <= j2; ++m2) {
      int m3 = m1 + m2;
      if (m3 < -j3 || m3 > j3) continue;
      double pref = std::sqrt((2 * j3 + 1) * factd(j1 + j2 - j3) * factd(j1 - j2 + j3) *
                              factd(-j1 + j2 + j3) / factd(j1 + j2 + j3 + 1));
      pref *= std::sqrt(factd(j1 + m1) * factd(j1 - m1) * factd(j2 + m2) *
                        factd(j2 - m2) * factd(j3 + m3) * factd(j3 - m3));
      int kmin = std::max(0, std::max(j2 - j3 - m1, j1 - j3 + m2));
      int kmax = std::min(j1 + j2 - j3, std::min(j1 - m1, j2 + m2));
      double s = 0.0;
      for (int k = kmin; k <= kmax; ++k) {
        s += ((k & 1) ? -1.0 : 1.0) /
             (factd(k) * factd(j1 + j2 - j3 - k) * factd(j1 - m1 - k) *
              factd(j2 + m2 - k) * factd(j3 - j2 + m1 + k) * factd(j3 - j1 - m2 + k));
      }
      C[((m1 + j1) * d2 + (m2 + j2)) * d3 + (m3 + j3)] = pref * s;
    }
}

static void umat(int l, std::vector<std::complex<double>>& U) {
  int d = 2 * l + 1;
  U.assign(d * d, std::complex<double>(0, 0));
  U[l * d + l] = 1.0;
  const double is2 = 1.0 / std::sqrt(2.0);
  for (int m = 1; m <= l; ++m) {
    double sg = (m & 1) ? -1.0 : 1.0;
    U[(l + m) * d + (l + m)] = sg * is2;
    U[(l + m) * d + (l - m)] = is2;
    U[(l - m) * d + (l + m)] = std::complex<double>(0, -sg * is2);
    U[(l - m) * d + (l - m)] = std::complex<double>(0, is2);
  }
}

static void real_cg(int l1, int l2, int l3, std::vector<double>& R) {
  std::vector<double> Cc;
  cg_complex(l1, l2, l3, Cc);
  std::vector<std::complex<double>> U1, U2, U3;
  umat(l1, U1); umat(l2, U2); umat(l3, U3);
  int d1 = 2 * l1 + 1, d2 = 2 * l2 + 1, d3 = 2 * l3 + 1;
  R.assign(d1 * d2 * d3, 0.0);
  for (int a = 0; a < d1; ++a)
    for (int b = 0; b < d2; ++b)
      for (int c = 0; c < d3; ++c) {
        std::complex<double> s(0, 0);
        for (int i = 0; i < d1; ++i)
          for (int j = 0; j < d2; ++j) {
            int k = (i - l1) + (j - l2) + l3;  // m3 = m1 + m2 selection rule
            if (k < 0 || k >= d3) continue;
            double cc = Cc[(i * d2 + j) * d3 + k];
            if (cc == 0.0) continue;
            s += U1[a * d1 + i] * U2[b * d2 + j] * std::conj(U3[c * d3 + k]) * cc;
          }
        R[(a * d2 + b) * d3 + c] = s.real();
      }
}

static void build_tab(CGTab& T) {
  static const int off_in[5] = {0, 1, 4, 9, 16};
  int nnz = 0, slot = 0;
  std::vector<double> R;
  for (int l1 = 0; l1 <= 3; ++l1)
    for (int l2 = 0; l2 <= 3; ++l2)
      for (int l3 = 0; l3 <= 4; ++l3) {
        if (!(std::abs(l1 - l2) <= l3 && l3 <= l1 + l2 && ((l1 + l2 + l3) % 2 == 0))) continue;
        real_cg(l1, l2, l3, R);
        int d2 = 2 * l2 + 1, d3 = 2 * l3 + 1;
        for (int c = 0; c < d3; ++c) {
          T.rowPtr[slot] = nnz;
          for (int a = 0; a < 2 * l1 + 1; ++a)
            for (int b = 0; b < d2; ++b) {
              double v = R[(a * d2 + b) * d3 + c];
              if (std::fabs(v) > 1e-8 && nnz < MAXNNZ) {
                T.ij[nnz] = (off_in[l1] + a) | ((off_in[l2] + b) << 8);
                T.co[nnz] = (float)v;
                ++nnz;
              }
            }
          ++slot;
        }
      }
  T.rowPtr[slot] = nnz;  // slot == 135
}

// ---------------- stage 1: per-(edge, slot) --------------------------------

__global__ __launch_bounds__(320) void edge_kernel(
    const float* __restrict__ disp, float* __restrict__ Pws,
    float* __restrict__ RCws, int nE) {
  __shared__ float Ysh[2][16];

  const int tid = threadIdx.x;
  const int half = (tid >= 160) ? 1 : 0;
  const int slot = tid - half * 160;
  const int e = blockIdx.x * 2 + half;

  if (e < nE && slot <= 8) {
    const float dx = disp[3 * e + 0], dy = disp[3 * e + 1], dz = disp[3 * e + 2];
    const float r = sqrtf(dx * dx + dy * dy + dz * dz + 1e-12f);
    if (slot < 8) {
      // one sinc term per thread: no serial 8x sinf chain anywhere
      const float s = r * 0.2f;          // r / CUTOFF
      const float s2 = s * s;
      const float cut = (s2 < 1.0f) ? expf(1.0f - 1.0f / (1.0f - s2)) : 0.0f;
      const float px = 3.14159265358979323846f * (float)(slot + 1) * s;
      RCws[e * 8 + slot] = cut * (sinf(px) / px);
    } else {  // slot == 8: spherical harmonics
      const float rinv = 1.0f / r;
      const float x = dx * rinv, y = dy * rinv, z = dz * rinv;
      const float x2 = x * x, y2 = y * y, z2 = z * z;
      float* q = &Ysh[half][0];
      q[0]  = 0.28209479177387814f;
      q[1]  = 0.4886025119029199f * y;
      q[2]  = 0.4886025119029199f * z;
      q[3]  = 0.4886025119029199f * x;
      q[4]  = 1.0925484305920792f * x * y;
      q[5]  = 1.0925484305920792f * y * z;
      q[6]  = 0.31539156525252005f * (3.0f * z2 - 1.0f);
      q[7]  = 1.0925484305920792f * x * z;
      q[8]  = 0.5462742152960396f * (x2 - y2);
      q[9]  = 0.5900435899266435f * y * (3.0f * x2 - y2);
      q[10] = 2.890611442640554f * x * y * z;
      q[11] = 0.4570457994644658f * y * (5.0f * z2 - 1.0f);
      q[12] = 0.3731763325901154f * z * (5.0f * z2 - 3.0f);
      q[13] = 0.4570457994644658f * x * (5.0f * z2 - 1.0f);
      q[14] = 1.445305721320277f * z * (x2 - y2);
      q[15] = 0.5900435899266435f * x * (x2 - 3.0f * y2);
    }
  }
  __syncthreads();

  if (e < nE && slot < 135) {
    const int b0 = d_tab.rowPtr[slot], b1 = d_tab.rowPtr[slot + 1];
    const float* Ye = &Ysh[half][0];
    float acc = 0.f;
    for (int t = b0; t < b1; ++t) {
      const int p = d_tab.ij[t];
      acc += d_tab.co[t] * Ye[p & 255] * Ye[(p >> 8) & 255];
    }
    Pws[(size_t)e * 136 + slot] = acc;
  }
}

// ---------------- stage 2: per-(edge, feature) — streaming write ------------

#define OUT_OFF(l3) ((l3) == 0 ? 0 : ((l3) == 1 ? 1 : ((l3) == 2 ? 4 : ((l3) == 3 ? 9 : 16))))

#define PATH(l1, l2, l3, sb)                                        \
  {                                                                 \
    const float t = R1v[l1] * R2v[l2];                              \
    _Pragma("unroll")                                               \
    for (int k = 0; k < 2 * (l3) + 1; ++k)                          \
      o[OUT_OFF(l3) + k] += t * Pl[(sb) + k];                       \
  }

__global__ __launch_bounds__(256) void feat_kernel(
    const float* __restrict__ W1, const float* __restrict__ W2,
    const float* __restrict__ Pws, const float* __restrict__ RCws,
    float* __restrict__ out, int nE) {
  __shared__ float P[4][136];
  __shared__ float RC[4][8];

  const int tid = threadIdx.x;
  const int eL = tid >> 6;
  const int f = tid & 63;
  const int e = blockIdx.x * 4 + eL;
  const int ec = e < nE ? e : nE - 1;

  // coalesced stage of P (135 floats) and radcut (8 floats) per edge
  for (int i = f; i < 135; i += 64) P[eL][i] = Pws[(size_t)ec * 136 + i];
  if (f < 8) RC[eL][f] = RCws[ec * 8 + f];
  __syncthreads();

  float rc[8];
#pragma unroll
  for (int k = 0; k < 8; ++k) rc[k] = RC[eL][k];

  float R1v[4], R2v[4];
#pragma unroll
  for (int l = 0; l < 4; ++l) {
    float a = 0.f, b = 0.f;
#pragma unroll
    for (int k = 0; k < 8; ++k) {
      a += rc[k] * W1[(l * 8 + k) * 64 + f];
      b += rc[k] * W2[(l * 8 + k) * 64 + f];
    }
    R1v[l] = a;
    R2v[l] = b;
  }

  const float* Pl = &P[eL][0];
  float o[25];
#pragma unroll
  for (int k = 0; k < 25; ++k) o[k] = 0.f;

  // (l1, l2, l3, slotBase) — parity-even triangle paths, reference order
  PATH(0, 0, 0, 0)   PATH(0, 1, 1, 1)   PATH(0, 2, 2, 4)   PATH(0, 3, 3, 9)
  PATH(1, 0, 1, 16)  PATH(1, 1, 0, 19)  PATH(1, 1, 2, 20)  PATH(1, 2, 1, 25)
  PATH(1, 2, 3, 28)  PATH(1, 3, 2, 35)  PATH(1, 3, 4, 40)
  PATH(2, 0, 2, 49)  PATH(2, 1, 1, 54)  PATH(2, 1, 3, 57)  PATH(2, 2, 0, 64)
  PATH(2, 2, 2, 65)  PATH(2, 2, 4, 70)  PATH(2, 3, 1, 79)  PATH(2, 3, 3, 82)
  PATH(3, 0, 3, 89)  PATH(3, 1, 2, 96)  PATH(3, 1, 4, 101) PATH(3, 2, 1, 110)
  PATH(3, 2, 3, 113) PATH(3, 3, 0, 120) PATH(3, 3, 2, 121) PATH(3, 3, 4, 126)

  // store: (e, k3, f), coalesced over f (256 B per wave-store)
  if (e < nE) {
    const size_t obase = (size_t)e * 1600 + f;  // 25*64
#pragma unroll
    for (int k3 = 0; k3 < 25; ++k3) out[obase + (size_t)k3 * 64] = o[k3];
  }
}

// ---------------- launch ----------------------------------------------------

extern "C" void kernel_launch(void* const* d_in, const int* in_sizes, int n_in,
                              void* d_out, int out_size, void* d_ws, size_t ws_size,
                              hipStream_t stream) {
  const float* disp = (const float*)d_in[0];
  const float* W1 = (const float*)d_in[1];
  const float* W2 = (const float*)d_in[2];
  float* out = (float*)d_out;

  const int nE = in_sizes[0] / 3;  // 4096*16 = 65536 edges

  // workspace layout: P[nE][136] then radcut[nE][8]
  float* Pws = (float*)d_ws;
  float* RCws = Pws + (size_t)nE * 136;
  // total: 65536*(136+8)*4 = 37.7 MB — well under ws_size

  // Deterministic host-side CG table, rebuilt every call (host work only runs
  // at capture/correctness time; the H2D copy is a captured graph node so it
  // replays before every timed launch, surviving the d_ws/d_out re-poison).
  static CGTab h_tab;
  build_tab(h_tab);
  void* sym = nullptr;
  (void)hipGetSymbolAddress(&sym, HIP_SYMBOL(d_tab));
  (void)hipMemcpyAsync(sym, &h_tab, sizeof(CGTab), hipMemcpyHostToDevice, stream);

  edge_kernel<<<(nE + 1) / 2, 320, 0, stream>>>(disp, Pws, RCws, nE);
  feat_kernel<<<(nE + 3) / 4, 256, 0, stream>>>(W1, W2, Pws, RCws, out, nE);
}

// Round 9
// 486.585 us; speedup vs baseline: 1.1418x; 1.1418x over previous
//
#include <hip/hip_runtime.h>
#include <cmath>
#include <complex>
#include <vector>
#include <algorithm>
#include <cstring>

// ---------------------------------------------------------------------------
// AtomCenteredTensorMomentDescriptor — fused single kernel, grid-stride.
//
// out[e,k3,f] = sum_paths R1[l1][f] R2[l2][f] * P[e][slot]
//   R{1,2}[l][f] = sum_k radcut[k] W{1,2}[l][k][f]   (rank-1 basis factorization)
//   P[e][slot]   = sum_nnz CG * Y_i * Y_j            (f-independent)
//
// r1 fused = ~193us, r3 split = ~218us (dur_us includes ~337us harness fills).
// This round: W in registers (kills ~54us of L1 re-reads), CG table in LDS,
// parallel sinf lanes, float4 stores via LDS-staged output.
// Floor: 419MB writes ~67us @ 6.3 TB/s.
// ---------------------------------------------------------------------------

#define MAXNNZ 2048
#define LDSNNZ 1536
#define EPG 4

struct CGTab {
  int   nnzTotal;
  int   rowPtr[136];   // CSR over 135 P-slots (rows padded to even length)
  int   ij[MAXNNZ];    // packed i | (j<<8), indices into Y[16]; pad entries = 0
  float co[MAXNNZ];    // CG coefficient; pad entries = 0.0f
};

__device__ CGTab d_tab;

// ---------------- host-side CG construction (exact port of reference) -------

static double factd(int n) { double f = 1.0; for (int i = 2; i <= n; ++i) f *= (double)i; return f; }

static void cg_complex(int j1, int j2, int j3, std::vector<double>& C) {
  int d2 = 2 * j2 + 1, d3 = 2 * j3 + 1;
  C.assign((2 * j1 + 1) * d2 * d3, 0.0);
  for (int m1 = -j1; m1 <= j1; ++m1)
    for (int m2 = -j2; m2 <= j2; ++m2) {
      int m3 = m1 + m2;
      if (m3 < -j3 || m3 > j3) continue;
      double pref = std::sqrt((2 * j3 + 1) * factd(j1 + j2 - j3) * factd(j1 - j2 + j3) *
                              factd(-j1 + j2 + j3) / factd(j1 + j2 + j3 + 1));
      pref *= std::sqrt(factd(j1 + m1) * factd(j1 - m1) * factd(j2 + m2) *
                        factd(j2 - m2) * factd(j3 + m3) * factd(j3 - m3));
      int kmin = std::max(0, std::max(j2 - j3 - m1, j1 - j3 + m2));
      int kmax = std::min(j1 + j2 - j3, std::min(j1 - m1, j2 + m2));
      double s = 0.0;
      for (int k = kmin; k <= kmax; ++k) {
        s += ((k & 1) ? -1.0 : 1.0) /
             (factd(k) * factd(j1 + j2 - j3 - k) * factd(j1 - m1 - k) *
              factd(j2 + m2 - k) * factd(j3 - j2 + m1 + k) * factd(j3 - j1 - m2 + k));
      }
      C[((m1 + j1) * d2 + (m2 + j2)) * d3 + (m3 + j3)] = pref * s;
    }
}

static void umat(int l, std::vector<std::complex<double>>& U) {
  int d = 2 * l + 1;
  U.assign(d * d, std::complex<double>(0, 0));
  U[l * d + l] = 1.0;
  const double is2 = 1.0 / std::sqrt(2.0);
  for (int m = 1; m <= l; ++m) {
    double sg = (m & 1) ? -1.0 : 1.0;
    U[(l + m) * d + (l + m)] = sg * is2;
    U[(l + m) * d + (l - m)] = is2;
    U[(l - m) * d + (l + m)] = std::complex<double>(0, -sg * is2);
    U[(l - m) * d + (l - m)] = std::complex<double>(0, is2);
  }
}

static void real_cg(int l1, int l2, int l3, std::vector<double>& R) {
  std::vector<double> Cc;
  cg_complex(l1, l2, l3, Cc);
  std::vector<std::complex<double>> U1, U2, U3;
  umat(l1, U1); umat(l2, U2); umat(l3, U3);
  int d1 = 2 * l1 + 1, d2 = 2 * l2 + 1, d3 = 2 * l3 + 1;
  R.assign(d1 * d2 * d3, 0.0);
  for (int a = 0; a < d1; ++a)
    for (int b = 0; b < d2; ++b)
      for (int c = 0; c < d3; ++c) {
        std::complex<double> s(0, 0);
        for (int i = 0; i < d1; ++i)
          for (int j = 0; j < d2; ++j) {
            int k = (i - l1) + (j - l2) + l3;  // m3 = m1 + m2 selection rule
            if (k < 0 || k >= d3) continue;
            double cc = Cc[(i * d2 + j) * d3 + k];
            if (cc == 0.0) continue;
            s += U1[a * d1 + i] * U2[b * d2 + j] * std::conj(U3[c * d3 + k]) * cc;
          }
        R[(a * d2 + b) * d3 + c] = s.real();
      }
}

static void build_tab(CGTab& T) {
  static const int off_in[5] = {0, 1, 4, 9, 16};
  int nnz = 0, slot = 0;
  std::vector<double> R;
  for (int l1 = 0; l1 <= 3; ++l1)
    for (int l2 = 0; l2 <= 3; ++l2)
      for (int l3 = 0; l3 <= 4; ++l3) {
        if (!(std::abs(l1 - l2) <= l3 && l3 <= l1 + l2 && ((l1 + l2 + l3) % 2 == 0))) continue;
        real_cg(l1, l2, l3, R);
        int d2 = 2 * l2 + 1, d3 = 2 * l3 + 1;
        for (int c = 0; c < d3; ++c) {
          T.rowPtr[slot] = nnz;
          for (int a = 0; a < 2 * l1 + 1; ++a)
            for (int b = 0; b < d2; ++b) {
              double v = R[(a * d2 + b) * d3 + c];
              if (std::fabs(v) > 1e-8 && nnz < MAXNNZ) {
                T.ij[nnz] = (off_in[l1] + a) | ((off_in[l2] + b) << 8);
                T.co[nnz] = (float)v;
                ++nnz;
              }
            }
          // pad row to even length for the unroll-2 device loop
          if ((nnz - T.rowPtr[slot]) & 1) {
            if (nnz < MAXNNZ) { T.ij[nnz] = 0; T.co[nnz] = 0.0f; ++nnz; }
          }
          ++slot;
        }
      }
  T.rowPtr[slot] = nnz;  // slot == 135
  T.nnzTotal = nnz;      // expected well under LDSNNZ (~700-1100 padded)
}

// ---------------- device kernel --------------------------------------------

#define OUT_OFF(l3) ((l3) == 0 ? 0 : ((l3) == 1 ? 1 : ((l3) == 2 ? 4 : ((l3) == 3 ? 9 : 16))))

#define PATH(l1, l2, l3, sb)                                        \
  {                                                                 \
    const float t = R1v[l1] * R2v[l2];                              \
    _Pragma("unroll")                                               \
    for (int k = 0; k < 2 * (l3) + 1; ++k)                          \
      o[OUT_OFF(l3) + k] += t * Pl[(sb) + k];                       \
  }

__global__ __launch_bounds__(256) void atmd_fused(
    const float* __restrict__ disp, const float* __restrict__ W1,
    const float* __restrict__ W2, float* __restrict__ out,
    int nE, int nGroups) {
  __shared__ int2  Tab[LDSNNZ];
  __shared__ int   RowP[136];
  __shared__ float Ysh[EPG][16];
  __shared__ float RCsh[EPG][8];
  __shared__ float Rsh[EPG][2][4][64];   // [edge][branch][l][f]
  __shared__ float Psh[EPG][136];
  __shared__ __align__(16) float Osh[EPG * 1600];

  const int tid = threadIdx.x;
  const int l = tid >> 6;        // wave id; doubles as W-row and local edge
  const int f = tid & 63;
  const int eL = l;

  // ---- once per block: CG table -> LDS ----
  const int nnz = d_tab.nnzTotal;
  for (int t = tid; t < nnz; t += 256)
    Tab[t] = make_int2(d_tab.ij[t], __float_as_int(d_tab.co[t]));
  for (int t = tid; t < 136; t += 256) RowP[t] = d_tab.rowPtr[t];

  // ---- once per block: W column f of branch rows -> registers ----
  float w1r[8], w2r[8];
#pragma unroll
  for (int k = 0; k < 8; ++k) {
    w1r[k] = W1[(l * 8 + k) * 64 + f];   // coalesced 256B per wave
    w2r[k] = W2[(l * 8 + k) * 64 + f];
  }

  for (int g = blockIdx.x; g < nGroups; g += gridDim.x) {
    const int ebase = g * EPG;
    __syncthreads();  // buffers free (prev group's readers done; Tab visible)

    // ---- geometry: wave eL, lanes 0..8 only ----
    const int e = ebase + eL;
    if (f <= 8 && e < nE) {
      const float dx = disp[3 * e + 0], dy = disp[3 * e + 1], dz = disp[3 * e + 2];
      const float r = sqrtf(dx * dx + dy * dy + dz * dz + 1e-12f);
      if (f >= 1) {
        // lanes 1..8: one sinc term each (parallel, not 8x serial)
        const float s = r * 0.2f;        // r / CUTOFF
        const float s2 = s * s;
        const float cutv = (s2 < 1.0f) ? expf(1.0f - 1.0f / (1.0f - s2)) : 0.0f;
        const float px = 3.14159265358979323846f * (float)f * s;
        RCsh[eL][f - 1] = cutv * (sinf(px) / px);
      } else {
        // lane 0: spherical harmonics l=0..3
        const float rinv = 1.0f / r;
        const float x = dx * rinv, y = dy * rinv, z = dz * rinv;
        const float x2 = x * x, y2 = y * y, z2 = z * z;
        float* q = &Ysh[eL][0];
        q[0]  = 0.28209479177387814f;
        q[1]  = 0.4886025119029199f * y;
        q[2]  = 0.4886025119029199f * z;
        q[3]  = 0.4886025119029199f * x;
        q[4]  = 1.0925484305920792f * x * y;
        q[5]  = 1.0925484305920792f * y * z;
        q[6]  = 0.31539156525252005f * (3.0f * z2 - 1.0f);
        q[7]  = 1.0925484305920792f * x * z;
        q[8]  = 0.5462742152960396f * (x2 - y2);
        q[9]  = 0.5900435899266435f * y * (3.0f * x2 - y2);
        q[10] = 2.890611442640554f * x * y * z;
        q[11] = 0.4570457994644658f * y * (5.0f * z2 - 1.0f);
        q[12] = 0.3731763325901154f * z * (5.0f * z2 - 3.0f);
        q[13] = 0.4570457994644658f * x * (5.0f * z2 - 1.0f);
        q[14] = 1.445305721320277f * z * (x2 - y2);
        q[15] = 0.5900435899266435f * x * (x2 - 3.0f * y2);
      }
    }
    __syncthreads();

    // ---- R-phase: thread (l,f) computes R1/R2[l][f] for all EPG edges ----
#pragma unroll
    for (int e4 = 0; e4 < EPG; ++e4) {
      float a = 0.f, b = 0.f;
#pragma unroll
      for (int k = 0; k < 8; ++k) {
        const float rc = RCsh[e4][k];    // wave-uniform broadcast read
        a += rc * w1r[k];
        b += rc * w2r[k];
      }
      Rsh[e4][0][l][f] = a;
      Rsh[e4][1][l][f] = b;
    }

    // ---- CSR phase: flat items over (edge, slot); rows even-length, unroll 2
    for (int w = tid; w < EPG * 135; w += 256) {
      const int e4 = w / 135;
      const int s  = w - e4 * 135;
      const int b0 = RowP[s], b1 = RowP[s + 1];
      const float* Ye = &Ysh[e4][0];
      float acc = 0.f;
      for (int t = b0; t < b1; t += 2) {
        const int2 en0 = Tab[t];
        const int2 en1 = Tab[t + 1];
        acc += __int_as_float(en0.y) * Ye[en0.x & 255] * Ye[(en0.x >> 8) & 255];
        acc += __int_as_float(en1.y) * Ye[en1.x & 255] * Ye[(en1.x >> 8) & 255];
      }
      Psh[e4][s] = acc;
    }
    __syncthreads();

    // ---- path phase: thread (eL, f) ----
    float R1v[4], R2v[4];
#pragma unroll
    for (int q = 0; q < 4; ++q) {
      R1v[q] = Rsh[eL][0][q][f];
      R2v[q] = Rsh[eL][1][q][f];
    }
    const float* Pl = &Psh[eL][0];
    float o[25];
#pragma unroll
    for (int k = 0; k < 25; ++k) o[k] = 0.f;

    PATH(0, 0, 0, 0)   PATH(0, 1, 1, 1)   PATH(0, 2, 2, 4)   PATH(0, 3, 3, 9)
    PATH(1, 0, 1, 16)  PATH(1, 1, 0, 19)  PATH(1, 1, 2, 20)  PATH(1, 2, 1, 25)
    PATH(1, 2, 3, 28)  PATH(1, 3, 2, 35)  PATH(1, 3, 4, 40)
    PATH(2, 0, 2, 49)  PATH(2, 1, 1, 54)  PATH(2, 1, 3, 57)  PATH(2, 2, 0, 64)
    PATH(2, 2, 2, 65)  PATH(2, 2, 4, 70)  PATH(2, 3, 1, 79)  PATH(2, 3, 3, 82)
    PATH(3, 0, 3, 89)  PATH(3, 1, 2, 96)  PATH(3, 1, 4, 101) PATH(3, 2, 1, 110)
    PATH(3, 2, 3, 113) PATH(3, 3, 0, 120) PATH(3, 3, 2, 121) PATH(3, 3, 4, 126)

    // stage output tile in LDS (lane-f layout -> block-flat layout)
    {
      float* Od = &Osh[eL * 1600 + f];
#pragma unroll
      for (int k3 = 0; k3 < 25; ++k3) Od[k3 * 64] = o[k3];
    }
    __syncthreads();

    // ---- store phase: contiguous float4 writes for the whole group ----
    {
      const int nvE = (nE - ebase) < EPG ? (nE - ebase) : EPG;
      const int n4 = nvE * 400;  // 1600 floats per edge = 400 float4
      const float4* Os4 = (const float4*)Osh;
      float4* out4 = (float4*)(out + (size_t)ebase * 1600);
      for (int i = tid; i < n4; i += 256) out4[i] = Os4[i];
    }
  }
}

// ---------------- launch ----------------------------------------------------

extern "C" void kernel_launch(void* const* d_in, const int* in_sizes, int n_in,
                              void* d_out, int out_size, void* d_ws, size_t ws_size,
                              hipStream_t stream) {
  const float* disp = (const float*)d_in[0];
  const float* W1 = (const float*)d_in[1];
  const float* W2 = (const float*)d_in[2];
  float* out = (float*)d_out;

  const int nE = in_sizes[0] / 3;          // 4096*16 = 65536 edges
  const int nGroups = (nE + EPG - 1) / EPG;

  // Deterministic host-side CG table; H2D copy is a captured graph node so it
  // replays before every timed launch (survives the d_out/d_ws re-poison).
  static CGTab h_tab;
  build_tab(h_tab);
  void* sym = nullptr;
  (void)hipGetSymbolAddress(&sym, HIP_SYMBOL(d_tab));
  (void)hipMemcpyAsync(sym, &h_tab, sizeof(CGTab), hipMemcpyHostToDevice, stream);

  const int grid = 2048;  // grid-stride; ~8 groups per block, 3 blocks/CU (49KB LDS)
  atmd_fused<<<grid, 256, 0, stream>>>(disp, W1, W2, out, nE, nGroups);
}